// Round 5
// baseline (358.394 us; speedup 1.0000x reference)
//
#include <hip/hip_runtime.h>
#include <hip/hip_bf16.h>

typedef unsigned short u16;
typedef __bf16 bf16x8_t __attribute__((ext_vector_type(8)));
typedef float f32x4_t __attribute__((ext_vector_type(4)));

struct alignas(8) us4 { u16 v[4]; };

__device__ __forceinline__ u16 f2bf(float f) {
  __hip_bfloat16 h = __float2bfloat16(f);
  u16 u; __builtin_memcpy(&u, &h, 2); return u;
}
__device__ __forceinline__ float bf2f(u16 u) {
  __hip_bfloat16 h; __builtin_memcpy(&h, &u, 2); return __bfloat162float(h);
}

__device__ __forceinline__ void gload16(const u16* g, u16* l) {
  __builtin_amdgcn_global_load_lds(
      (const __attribute__((address_space(1))) void*)g,
      (__attribute__((address_space(3))) void*)l, 16, 0, 0);
}

#define M_PROJQ 0
#define M_PROJT 1
#define M_PLAIN 2
#define M_OUT   3
#define M_FINAL 4

// C[m][n] = sum_k A[m][k] * Bt[n][k], bf16, 128xBN tile, BK=32, 2-phase dbuf.
// PROJ modes: N-tile is h-interleaved (tile col c = h*16 + e_lo, e = bx*16+e_lo);
//   SM=true fuses softmax-over-heads into the epilogue (LDS cross-wave exchange).
//   M_PROJQ writes qsP[b][s][ (d>>4)*128 + h*16 + (d&15) ] (coalesced rows).
//   M_PROJT writes [b,h,e,s] (transposed, coalesced 256B rows).
// M_OUT: A = qsP with permuted k-addressing (KA=256 step), z=(b,h).
// M_FINAL: z = K-split chunk, fp32 partials, no bias.
template<int MODE, int BN, bool SM>
__global__ __launch_bounds__(256, 2)
void gemm_kernel(const u16* __restrict__ A, long sAz, int lda,
                 const u16* __restrict__ B, long sBz, int ldb,
                 const float* __restrict__ bias,
                 void* __restrict__ Cv, long sCz, int ldc,
                 int nx, int K)
{
  constexpr int NJ = BN / 32;            // 16-col frags per wave
  constexpr int BUFS = 4096 + BN * 32;   // u16 per dbuf buffer
  constexpr int CW = BN + 8;             // Cs padded width
  __shared__ __align__(16) u16 smem[17408];

  // XCD-bijective swizzle (gridDim.x % 8 == 0 for all launches here)
  const int nwg = gridDim.x;
  const int chunk = nwg >> 3;
  const int bid = blockIdx.x;
  const int wg = (bid & 7) * chunk + (bid >> 3);
  const int nxy = nx * ((MODE == M_PLAIN) ? 4 : (MODE == M_OUT ? 16 : 64));
  const int z = wg / nxy;
  const int rem = wg - z * nxy;
  const int by = rem / nx;
  const int bx = rem - by * nx;

  const int tid = threadIdx.x;
  const int lane = tid & 63;
  const int wave = tid >> 6;
  const int wm = (wave >> 1) * 64;
  const int wn = (wave & 1) * (BN / 2);
  const int m0 = by * 128;
  const int n0 = bx * BN;

  const int srow = tid >> 2;            // 0..63
  const int scol = (tid & 3) * 8;       // 0,8,16,24

  // A pointers
  const u16* Az;
  long aoff0;
  if constexpr (MODE == M_OUT) {
    Az = A + (long)(z >> 3) * 8388608;
    aoff0 = (long)(m0 + srow) * lda + (z & 7) * 16 + (scol & 8) + (scol >> 4) * 128;
  } else {
    Az = A + (long)z * sAz;
    aoff0 = (long)(m0 + srow) * lda + scol;
  }
  const u16* aptr0 = Az + aoff0;
  const u16* aptr1 = aptr0 + (long)64 * lda;
  constexpr int KA = (MODE == M_OUT) ? 256 : 32;

  // B pointers
  const u16* Bz = B + (long)z * sBz;
  const u16* bptr0;
  const u16* bptr1;
  if constexpr (MODE == M_PROJQ || MODE == M_PROJT) {
    const int brow0 = (srow >> 4) * 512 + bx * 16 + (srow & 15);
    bptr0 = Bz + (long)brow0 * ldb + scol;
    bptr1 = bptr0 + (long)2048 * ldb;
  } else {
    bptr0 = Bz + (long)(n0 + srow) * ldb + scol;
    bptr1 = bptr0 + (long)64 * ldb;
  }

  f32x4_t acc[4][NJ];
#pragma unroll
  for (int i = 0; i < 4; i++)
#pragma unroll
    for (int j = 0; j < NJ; j++) acc[i][j] = (f32x4_t){0.f, 0.f, 0.f, 0.f};

  const int kk = (lane >> 4) * 8;
  const int fr = lane & 15;
  const int nt = K >> 5;

  int aoffL[4], boffL[NJ];
#pragma unroll
  for (int i = 0; i < 4; i++) aoffL[i] = (wm + i * 16 + fr) * 32 + kk;
#pragma unroll
  for (int j = 0; j < NJ; j++) boffL[j] = 4096 + (wn + j * 16 + fr) * 32 + kk;

  // prologue: stage tile 0 into buf 0
  gload16(aptr0, smem + tid * 8);
  gload16(aptr1, smem + 2048 + tid * 8);
  gload16(bptr0, smem + 4096 + tid * 8);
  if constexpr (BN == 128) gload16(bptr1, smem + 6144 + tid * 8);
  __syncthreads();

  int cur = 0;
  for (int t = 0; t < nt - 1; t++) {
    const u16* cb = smem + cur * BUFS;
    bf16x8_t afr[4], bfr[NJ];
#pragma unroll
    for (int i = 0; i < 4; i++) afr[i] = *(const bf16x8_t*)&cb[aoffL[i]];
#pragma unroll
    for (int j = 0; j < NJ; j++) bfr[j] = *(const bf16x8_t*)&cb[boffL[j]];
    u16* nb = smem + (cur ^ 1) * BUFS;
    const long ka = (long)(t + 1) * KA;
    const int kb_ = (t + 1) * 32;
    gload16(aptr0 + ka, nb + tid * 8);
    gload16(aptr1 + ka, nb + 2048 + tid * 8);
    gload16(bptr0 + kb_, nb + 4096 + tid * 8);
    if constexpr (BN == 128) gload16(bptr1 + kb_, nb + 6144 + tid * 8);
#pragma unroll
    for (int i = 0; i < 4; i++)
#pragma unroll
      for (int j = 0; j < NJ; j++)
        acc[i][j] = __builtin_amdgcn_mfma_f32_16x16x32_bf16(afr[i], bfr[j], acc[i][j], 0, 0, 0);
    __syncthreads();
    cur ^= 1;
  }
  {  // last tile: compute only
    const u16* cb = smem + cur * BUFS;
    bf16x8_t afr[4], bfr[NJ];
#pragma unroll
    for (int i = 0; i < 4; i++) afr[i] = *(const bf16x8_t*)&cb[aoffL[i]];
#pragma unroll
    for (int j = 0; j < NJ; j++) bfr[j] = *(const bf16x8_t*)&cb[boffL[j]];
#pragma unroll
    for (int i = 0; i < 4; i++)
#pragma unroll
      for (int j = 0; j < NJ; j++)
        acc[i][j] = __builtin_amdgcn_mfma_f32_16x16x32_bf16(afr[i], bfr[j], acc[i][j], 0, 0, 0);
  }
  __syncthreads();  // all LDS reads done; smem reusable

  // ---- fused softmax over heads (PROJ modes, SM=true) ----
  if constexpr (SM) {
    // lane holds rows wm+i*16+(lane>>4)*4+r, cols h=(wn>>4)+j (j=0..3), e=bx*16+fr.
    // Partner wave (wave^1) holds the other 4 heads for identical rows/e.
    float* ex = (float*)smem;          // 4096 floats
    float* ex2 = ex + 4096;            // 4096 floats
    const int wmg = wave >> 1, wng = wave & 1;
    const int self = ((wmg * 2 + wng) * 64 + lane) * 16;
    const int part = ((wmg * 2 + (wng ^ 1)) * 64 + lane) * 16;
    float bj[4];
#pragma unroll
    for (int j = 0; j < 4; j++) bj[j] = bias[((wn >> 4) + j) * 512 + bx * 16 + fr];
#pragma unroll
    for (int i = 0; i < 4; i++)
#pragma unroll
      for (int j = 0; j < 4; j++)
#pragma unroll
        for (int r = 0; r < 4; r++) acc[i][j][r] += bj[j];
    float mx[16];
#pragma unroll
    for (int i = 0; i < 4; i++)
#pragma unroll
      for (int r = 0; r < 4; r++) {
        float m = acc[i][0][r];
#pragma unroll
        for (int j = 1; j < 4; j++) m = fmaxf(m, acc[i][j][r]);
        mx[i * 4 + r] = m;
      }
#pragma unroll
    for (int t = 0; t < 16; t++) ex[self + t] = mx[t];
    __syncthreads();
#pragma unroll
    for (int t = 0; t < 16; t++) mx[t] = fmaxf(mx[t], ex[part + t]);
    float sm[16];
#pragma unroll
    for (int t = 0; t < 16; t++) sm[t] = 0.f;
#pragma unroll
    for (int i = 0; i < 4; i++)
#pragma unroll
      for (int j = 0; j < 4; j++)
#pragma unroll
        for (int r = 0; r < 4; r++) {
          float p = __expf(acc[i][j][r] - mx[i * 4 + r]);
          acc[i][j][r] = p;
          sm[i * 4 + r] += p;
        }
#pragma unroll
    for (int t = 0; t < 16; t++) ex2[self + t] = sm[t];
    __syncthreads();
#pragma unroll
    for (int t = 0; t < 16; t++) sm[t] = 1.f / (sm[t] + ex2[part + t]);
#pragma unroll
    for (int i = 0; i < 4; i++)
#pragma unroll
      for (int j = 0; j < 4; j++)
#pragma unroll
        for (int r = 0; r < 4; r++) acc[i][j][r] *= sm[i * 4 + r];
    __syncthreads();  // exchange reads done before Cs reuse
  }

  // C/D frag layout: col = lane&15 (+wn+j*16), row = (lane>>4)*4 + reg (+wm+i*16)
  if constexpr (MODE == M_FINAL) {
    float* o = (float*)Cv + (long)z * sCz;
#pragma unroll
    for (int i = 0; i < 4; i++) {
      const int rbase = m0 + wm + i * 16 + ((lane >> 4) << 2);
#pragma unroll
      for (int j = 0; j < 4; j++) {
        const int gc = n0 + wn + j * 16 + fr;
#pragma unroll
        for (int r = 0; r < 4; r++)
          o[(long)(rbase + r) * ldc + gc] = acc[i][j][r];
      }
    }
    return;
  }

  // ---- LDS-staged epilogue: Cs[128][CW] ----
  u16* Cs = smem;
  if constexpr (MODE == M_PROJT) {
    // transposed tile: Cs[row = tile col c][col = s]
#pragma unroll
    for (int j = 0; j < 4; j++) {
      const int c = wn + j * 16 + fr;
      const float bb = SM ? 0.f : bias[((wn >> 4) + j) * 512 + bx * 16 + fr];
#pragma unroll
      for (int i = 0; i < 4; i++) {
        us4 w;
#pragma unroll
        for (int r = 0; r < 4; r++) w.v[r] = f2bf(acc[i][j][r] + bb);
        *(us4*)&Cs[c * CW + wm + i * 16 + ((lane >> 4) << 2)] = w;
      }
    }
  } else {
#pragma unroll
    for (int j = 0; j < NJ; j++) {
      const int c = wn + j * 16 + fr;
#pragma unroll
      for (int i = 0; i < 4; i++) {
        const int rbase = wm + i * 16 + ((lane >> 4) << 2);
#pragma unroll
        for (int r = 0; r < 4; r++)
          Cs[(rbase + r) * CW + c] = f2bf(acc[i][j][r]);
      }
    }
  }
  __syncthreads();

  // ---- coalesced copy-out ----
  u16* dst = (u16*)Cv;
  if constexpr (MODE == M_PROJQ) {
    // qsP[b][s][bx*128 + c], rows 4096 wide
    const int b = m0 >> 11, s0 = m0 & 2047;
    const long base = (long)b * 8388608 + (long)s0 * 4096 + bx * 128;
#pragma unroll
    for (int it = 0; it < 8; it++) {
      const int idx = it * 256 + tid;
      const int row = idx >> 4, ch = idx & 15;
      *(uint4*)&dst[base + (long)row * 4096 + ch * 8] = *(const uint4*)&Cs[row * CW + ch * 8];
    }
  } else if constexpr (MODE == M_PROJT) {
    // [b,h,e,s]: row c -> h=c>>4, e=bx*16+(c&15)
    const int b = m0 >> 11, s0 = m0 & 2047;
#pragma unroll
    for (int it = 0; it < 8; it++) {
      const int idx = it * 256 + tid;
      const int row = idx >> 4, ch = idx & 15;
      const long base = (long)(b * 8 + (row >> 4)) * 1048576 +
                        (long)(bx * 16 + (row & 15)) * 2048 + s0;
      *(uint4*)&dst[base + ch * 8] = *(const uint4*)&Cs[row * CW + ch * 8];
    }
  } else if constexpr (MODE == M_PLAIN) {
    const long base = (long)z * sCz + (long)m0 * ldc + n0;
    constexpr int CH = BN / 8;  // 16B chunks per row
#pragma unroll
    for (int it = 0; it < 128 * CH / 256; it++) {
      const int idx = it * 256 + tid;
      const int row = idx / CH, ch = idx % CH;
      *(uint4*)&dst[base + (long)row * ldc + ch * 8] = *(const uint4*)&Cs[row * CW + ch * 8];
    }
  } else {  // M_OUT: out2[b][s][h*512 + n0 + c]
    const long base = (long)(z >> 3) * 8388608 + (long)m0 * 4096 + (z & 7) * 512 + n0;
#pragma unroll
    for (int it = 0; it < 8; it++) {
      const int idx = it * 256 + tid;
      const int row = idx >> 4, ch = idx & 15;
      *(uint4*)&dst[base + (long)row * 4096 + ch * 8] = *(const uint4*)&Cs[row * CW + ch * 8];
    }
  }
}

// merged fp32 -> bf16 convert of q,k,v (2048 blocks each)
__global__ void cvt3_kernel(const float* __restrict__ q, const float* __restrict__ k,
                            const float* __restrict__ v, u16* __restrict__ qb,
                            u16* __restrict__ kb, u16* __restrict__ vb) {
  const int arr = blockIdx.x >> 11;
  const int lb = blockIdx.x & 2047;
  const float* in = arr == 0 ? q : (arr == 1 ? k : v);
  u16* out = arr == 0 ? qb : (arr == 1 ? kb : vb);
  const long i = ((long)lb * 256 + threadIdx.x) * 8;
  float4 a = *(const float4*)(in + i);
  float4 b = *(const float4*)(in + i + 4);
  u16 t[8] = {f2bf(a.x), f2bf(a.y), f2bf(a.z), f2bf(a.w),
              f2bf(b.x), f2bf(b.y), f2bf(b.z), f2bf(b.w)};
  uint4 w; __builtin_memcpy(&w, t, 16);
  *(uint4*)(out + i) = w;
}

// merged Wq/Wk/Wv transpose+convert: out[z][c][r] = bf16(in[z][r][c]), 512x512 x8 each
__global__ void tcvt3_kernel(const float* __restrict__ Wq, const float* __restrict__ Wk,
                             const float* __restrict__ Wv, u16* __restrict__ WqT,
                             u16* __restrict__ WkT, u16* __restrict__ WvT)
{
  __shared__ float tile[32][33];
  const int arr = blockIdx.z >> 3;
  const int zz = blockIdx.z & 7;
  const float* in = arr == 0 ? Wq : (arr == 1 ? Wk : Wv);
  u16* out = arr == 0 ? WqT : (arr == 1 ? WkT : WvT);
  const long zoff = (long)zz * 262144;
  const float* inz = in + zoff;
  u16* outz = out + zoff;
  const int c0 = blockIdx.x * 32, r0 = blockIdx.y * 32;
#pragma unroll
  for (int yy = threadIdx.y; yy < 32; yy += 8)
    tile[yy][threadIdx.x] = inz[(long)(r0 + yy) * 512 + c0 + threadIdx.x];
  __syncthreads();
#pragma unroll
  for (int yy = threadIdx.y; yy < 32; yy += 8)
    outz[(long)(c0 + yy) * 512 + r0 + threadIdx.x] = f2bf(tile[threadIdx.x][yy]);
}

// WoT[f][c] = bf16(Wo[(c&511)*8 + (c>>9)][f]); Wo [4096][512] fp32, WoT [512][4096]
__global__ void tcvt_wo(const float* __restrict__ in, u16* __restrict__ out) {
  __shared__ float tile[32][33];
  const int c0 = blockIdx.x * 32, f0 = blockIdx.y * 32;
  const int h = c0 >> 9, j0 = c0 & 511;
#pragma unroll
  for (int yy = threadIdx.y; yy < 32; yy += 8)
    tile[yy][threadIdx.x] = in[(long)((j0 + yy) * 8 + h) * 512 + f0 + threadIdx.x];
  __syncthreads();
#pragma unroll
  for (int yy = threadIdx.y; yy < 32; yy += 8)
    out[(long)(f0 + yy) * 4096 + c0 + threadIdx.x] = f2bf(tile[threadIdx.x][yy]);
}

// sum 4 fp32 K-split partials + bias -> fp32 out; 8192x512 elems, float4
__global__ void reduce4_kernel(const float* __restrict__ p, const float* __restrict__ bo,
                               float* __restrict__ out)
{
  const long S = 8192L * 512;
  const long i4 = ((long)blockIdx.x * 256 + threadIdx.x) * 4;
  float4 a = *(const float4*)(p + i4);
  float4 b = *(const float4*)(p + S + i4);
  float4 c = *(const float4*)(p + 2 * S + i4);
  float4 d = *(const float4*)(p + 3 * S + i4);
  float4 bb = *(const float4*)(bo + (i4 & 511));
  float4 r;
  r.x = a.x + b.x + c.x + d.x + bb.x;
  r.y = a.y + b.y + c.y + d.y + bb.y;
  r.z = a.z + b.z + c.z + d.z + bb.z;
  r.w = a.w + b.w + c.w + d.w + bb.w;
  *(float4*)(out + i4) = r;
}

extern "C" void kernel_launch(void* const* d_in, const int* in_sizes, int n_in,
                              void* d_out, int out_size, void* d_ws, size_t ws_size,
                              hipStream_t stream) {
  const float* q  = (const float*)d_in[0];
  const float* k  = (const float*)d_in[1];
  const float* v  = (const float*)d_in[2];
  const float* Wq = (const float*)d_in[3];
  const float* bq = (const float*)d_in[4];
  const float* Wk = (const float*)d_in[5];
  const float* bk = (const float*)d_in[6];
  const float* Wv = (const float*)d_in[7];
  const float* bv = (const float*)d_in[8];
  const float* Wo = (const float*)d_in[9];
  const float* bo = (const float*)d_in[10];
  float* outp = (float*)d_out;

  char* ws = (char*)d_ws;
  // time-aliased layout (peak 212 MiB):
  u16* qs   = (u16*)(ws);                  //   0- 64 MiB qsP [b][s][perm(h,d)]
  float* Pf = (float*)(ws);                //   0- 64 MiB fp32 K-split partials (qs dead)
  u16* WqT  = (u16*)(ws + (64L  << 20));   //  64- 68     dead before ksT written
  u16* qb   = (u16*)(ws + (72L  << 20));   //  72- 80     dead before ksT written
  u16* ksT  = (u16*)(ws + (64L  << 20));   //  64-128 [b,h,e,s]; later out2
  u16* out2 = ksT;                         //  64-128 [b,s,(h*512+j)]
  u16* kb   = (u16*)(ws + (128L << 20));   // 128-136     dead before vsT written
  u16* vsT  = (u16*)(ws + (128L << 20));   // 128-192 [b,h,e,s]
  u16* vb   = (u16*)(ws + (192L << 20));   // 192-200     dead before ctxT written
  u16* WkT  = (u16*)(ws + (200L << 20));   // 200-204     dead before ctxT written
  u16* WvT  = (u16*)(ws + (204L << 20));   // 204-208     dead before ctxT written
  u16* ctxT = (u16*)(ws + (192L << 20));   // 192-208 [b,h][j][d]
  u16* WoT  = (u16*)(ws + (208L << 20));   // 208-212 [f][h*512+j]

  // 1. fp32 -> bf16 inputs
  cvt3_kernel<<<6144, 256, 0, stream>>>(q, k, v, qb, kb, vb);

  // 2. weight transposes
  dim3 tb(32, 8, 1);
  tcvt3_kernel<<<dim3(16, 16, 24), tb, 0, stream>>>(Wq, Wk, Wv, WqT, WkT, WvT);
  tcvt_wo<<<dim3(128, 16, 1), tb, 0, stream>>>(Wo, WoT);

  // 3-5. projections (softmax fused for q,k): M=8192, N=4096(h-interleaved), K=512
  gemm_kernel<M_PROJQ, 128, true><<<2048, 256, 0, stream>>>(
      qb, 0, 512, WqT, 0, 512, bq, qs, 0, 0, 32, 512);
  gemm_kernel<M_PROJT, 128, true><<<2048, 256, 0, stream>>>(
      kb, 0, 512, WkT, 0, 512, bk, ksT, 0, 0, 32, 512);
  gemm_kernel<M_PROJT, 128, false><<<2048, 256, 0, stream>>>(
      vb, 0, 512, WvT, 0, 512, bv, vsT, 0, 0, 32, 512);

  // 6. ctxT[b,h][j][d] = sum_s vsT[j][s]*ksT[d][s]; BN=64: nx=8, ny=4, nz=32 -> 1024
  gemm_kernel<M_PLAIN, 64, false><<<1024, 256, 0, stream>>>(
      vsT, 1048576, 2048, ksT, 1048576, 2048, nullptr, ctxT, 262144, 512, 8, 2048);

  // 7. out2[b][s][h*512+j] = sum_d qsP[s][perm(h,d)]*ctxT[j][d]; nx=4, ny=16, nz=32
  gemm_kernel<M_OUT, 128, false><<<2048, 256, 0, stream>>>(
      qs, 0, 4096, ctxT, 262144, 512, nullptr, out2, 0, 0, 4, 512);

  // 8. final partials: K=4096 split 4x1024; nx=4, ny=64, nz=4 -> 1024 blocks
  gemm_kernel<M_FINAL, 128, false><<<1024, 256, 0, stream>>>(
      out2, 1024, 4096, WoT, 1024, 4096, nullptr, Pf, 8192L * 512, 512, 4, 1024);

  // 9. reduce partials + bias -> fp32 out
  reduce4_kernel<<<4096, 256, 0, stream>>>(Pf, bo, outp);
}

// Round 6
// 356.592 us; speedup vs baseline: 1.0051x; 1.0051x over previous
//
#include <hip/hip_runtime.h>
#include <hip/hip_bf16.h>

typedef unsigned short u16;
typedef __bf16 bf16x8_t __attribute__((ext_vector_type(8)));
typedef float f32x4_t __attribute__((ext_vector_type(4)));

struct alignas(8) us4 { u16 v[4]; };

__device__ __forceinline__ u16 f2bf(float f) {
  __hip_bfloat16 h = __float2bfloat16(f);
  u16 u; __builtin_memcpy(&u, &h, 2); return u;
}
__device__ __forceinline__ float bf2f(u16 u) {
  __hip_bfloat16 h; __builtin_memcpy(&h, &u, 2); return __bfloat162float(h);
}

__device__ __forceinline__ void gload16(const u16* g, u16* l) {
  __builtin_amdgcn_global_load_lds(
      (const __attribute__((address_space(1))) void*)g,
      (__attribute__((address_space(3))) void*)l, 16, 0, 0);
}

#define M_PROJQ 0
#define M_PROJT 1
#define M_PLAIN 2
#define M_OUT   3
#define M_FINAL 4

// C[m][n] = sum_k A[m][k] * Bt[n][k], bf16, 128xBN tile, BK=32.
// 3-buffer depth-2 prefetch: counted s_waitcnt vmcnt(GL) + raw s_barrier per
// step (loads for tiles t+1, t+2 stay in flight across barriers — T4).
// PROJ modes: weights are PRE-interleaved (row' = (e>>4)*128 + h*16 + (e&15)),
// so B staging is contiguous; tile col c -> h = c>>4, e = bx*16 + (c&15).
// SM=true fuses softmax-over-heads into the epilogue (cross-wave LDS exchange).
// M_PROJQ writes qsP[b][s][(d>>4)*128 + h*16 + (d&15)] (coalesced rows).
// M_PROJT writes [b,h,e,s]. M_OUT reads qsP via permuted k-addressing (KA=256).
// M_FINAL: z = K-split chunk, fp32 partials, no bias.
template<int MODE, int BN, bool SM>
__global__ __launch_bounds__(256, 2)
void gemm_kernel(const u16* __restrict__ A, long sAz, int lda,
                 const u16* __restrict__ B, long sBz, int ldb,
                 const float* __restrict__ bias,
                 void* __restrict__ Cv, long sCz, int ldc,
                 int nx, int K)
{
  constexpr int NJ = BN / 32;            // 16-col frags per wave
  constexpr int BUFS = 4096 + BN * 32;   // u16 per staging buffer
  constexpr int CW = BN + 8;             // Cs padded width
  constexpr int GL = 2 + BN / 64;        // gload instrs per tile per wave
  __shared__ __align__(16) u16 smem[3 * BUFS];

  // XCD-bijective swizzle (gridDim.x % 8 == 0 for all launches here)
  const int nwg = gridDim.x;
  const int chunk = nwg >> 3;
  const int bid = blockIdx.x;
  const int wg = (bid & 7) * chunk + (bid >> 3);
  const int nxy = nx * ((MODE == M_PLAIN) ? 4 : (MODE == M_OUT ? 16 : 64));
  const int z = wg / nxy;
  const int rem = wg - z * nxy;
  const int by = rem / nx;
  const int bx = rem - by * nx;

  const int tid = threadIdx.x;
  const int lane = tid & 63;
  const int wave = tid >> 6;
  const int wm = (wave >> 1) * 64;
  const int wn = (wave & 1) * (BN / 2);
  const int m0 = by * 128;
  const int n0 = bx * BN;

  const int srow = tid >> 2;            // 0..63
  const int scol = (tid & 3) * 8;       // 0,8,16,24

  // A pointers
  const u16* Az;
  long aoff0;
  if constexpr (MODE == M_OUT) {
    Az = A + (long)(z >> 3) * 8388608;
    aoff0 = (long)(m0 + srow) * lda + (z & 7) * 16 + (scol & 8) + (scol >> 4) * 128;
  } else {
    Az = A + (long)z * sAz;
    aoff0 = (long)(m0 + srow) * lda + scol;
  }
  const u16* aptr0 = Az + aoff0;
  const u16* aptr1 = aptr0 + (long)64 * lda;
  constexpr int KA = (MODE == M_OUT) ? 256 : 32;

  // B pointers (contiguous rows; weights pre-interleaved for PROJ modes)
  const u16* Bz = B + (long)z * sBz;
  const u16* bptr0 = Bz + (long)(n0 + srow) * ldb + scol;
  const u16* bptr1 = bptr0 + (long)64 * ldb;

  f32x4_t acc[4][NJ];
#pragma unroll
  for (int i = 0; i < 4; i++)
#pragma unroll
    for (int j = 0; j < NJ; j++) acc[i][j] = (f32x4_t){0.f, 0.f, 0.f, 0.f};

  const int kk = (lane >> 4) * 8;
  const int fr = lane & 15;
  const int nt = K >> 5;

  int aoffL[4], boffL[NJ];
#pragma unroll
  for (int i = 0; i < 4; i++) aoffL[i] = (wm + i * 16 + fr) * 32 + kk;
#pragma unroll
  for (int j = 0; j < NJ; j++) boffL[j] = 4096 + (wn + j * 16 + fr) * 32 + kk;

  auto stage = [&](int t, u16* nb) {
    const long ka = (long)t * KA;
    const int kb_ = t * 32;
    gload16(aptr0 + ka, nb + tid * 8);
    gload16(aptr1 + ka, nb + 2048 + tid * 8);
    gload16(bptr0 + kb_, nb + 4096 + tid * 8);
    if constexpr (BN == 128) gload16(bptr1 + kb_, nb + 6144 + tid * 8);
  };

  // prologue: tiles 0,1 into bufs 0,1
  stage(0, smem);
  stage(1, smem + BUFS);

  for (int t = 0; t < nt; t++) {
    if (t < nt - 1) asm volatile("s_waitcnt vmcnt(%0)" :: "i"(GL) : "memory");
    else            asm volatile("s_waitcnt vmcnt(0)" ::: "memory");
    __builtin_amdgcn_s_barrier();
    asm volatile("" ::: "memory");
    if (t + 2 < nt) stage(t + 2, smem + ((t + 2) % 3) * BUFS);
    const u16* cb = smem + (t % 3) * BUFS;
    bf16x8_t afr[4], bfr[NJ];
#pragma unroll
    for (int i = 0; i < 4; i++) afr[i] = *(const bf16x8_t*)&cb[aoffL[i]];
#pragma unroll
    for (int j = 0; j < NJ; j++) bfr[j] = *(const bf16x8_t*)&cb[boffL[j]];
#pragma unroll
    for (int i = 0; i < 4; i++)
#pragma unroll
      for (int j = 0; j < NJ; j++)
        acc[i][j] = __builtin_amdgcn_mfma_f32_16x16x32_bf16(afr[i], bfr[j], acc[i][j], 0, 0, 0);
  }
  __syncthreads();  // full drain before smem reuse

  // ---- fused softmax over heads (PROJ modes, SM=true) ----
  if constexpr (SM) {
    // lane holds rows wm+i*16+(lane>>4)*4+r, cols h=(wn>>4)+j (j=0..3), e=bx*16+fr.
    // Partner wave (wave^1) holds the other 4 heads for identical rows/e.
    float* ex = (float*)smem;          // 4096 floats
    float* ex2 = ex + 4096;            // 4096 floats
    const int wmg = wave >> 1, wng = wave & 1;
    const int self = ((wmg * 2 + wng) * 64 + lane) * 16;
    const int part = ((wmg * 2 + (wng ^ 1)) * 64 + lane) * 16;
    float bj[4];
#pragma unroll
    for (int j = 0; j < 4; j++) bj[j] = bias[((wn >> 4) + j) * 512 + bx * 16 + fr];
#pragma unroll
    for (int i = 0; i < 4; i++)
#pragma unroll
      for (int j = 0; j < 4; j++)
#pragma unroll
        for (int r = 0; r < 4; r++) acc[i][j][r] += bj[j];
    float mx[16];
#pragma unroll
    for (int i = 0; i < 4; i++)
#pragma unroll
      for (int r = 0; r < 4; r++) {
        float m = acc[i][0][r];
#pragma unroll
        for (int j = 1; j < 4; j++) m = fmaxf(m, acc[i][j][r]);
        mx[i * 4 + r] = m;
      }
#pragma unroll
    for (int t = 0; t < 16; t++) ex[self + t] = mx[t];
    __syncthreads();
#pragma unroll
    for (int t = 0; t < 16; t++) mx[t] = fmaxf(mx[t], ex[part + t]);
    float sm[16];
#pragma unroll
    for (int t = 0; t < 16; t++) sm[t] = 0.f;
#pragma unroll
    for (int i = 0; i < 4; i++)
#pragma unroll
      for (int j = 0; j < 4; j++)
#pragma unroll
        for (int r = 0; r < 4; r++) {
          float p = __expf(acc[i][j][r] - mx[i * 4 + r]);
          acc[i][j][r] = p;
          sm[i * 4 + r] += p;
        }
#pragma unroll
    for (int t = 0; t < 16; t++) ex2[self + t] = sm[t];
    __syncthreads();
#pragma unroll
    for (int t = 0; t < 16; t++) sm[t] = 1.f / (sm[t] + ex2[part + t]);
#pragma unroll
    for (int i = 0; i < 4; i++)
#pragma unroll
      for (int j = 0; j < 4; j++)
#pragma unroll
        for (int r = 0; r < 4; r++) acc[i][j][r] *= sm[i * 4 + r];
    __syncthreads();  // exchange reads done before Cs reuse
  }

  // C/D frag layout: col = lane&15 (+wn+j*16), row = (lane>>4)*4 + reg (+wm+i*16)
  if constexpr (MODE == M_FINAL) {
    float* o = (float*)Cv + (long)z * sCz;
#pragma unroll
    for (int i = 0; i < 4; i++) {
      const int rbase = m0 + wm + i * 16 + ((lane >> 4) << 2);
#pragma unroll
      for (int j = 0; j < 4; j++) {
        const int gc = n0 + wn + j * 16 + fr;
#pragma unroll
        for (int r = 0; r < 4; r++)
          o[(long)(rbase + r) * ldc + gc] = acc[i][j][r];
      }
    }
    return;
  }

  // ---- LDS-staged epilogue: Cs[128][CW] ----
  u16* Cs = smem;
  if constexpr (MODE == M_PROJT) {
    // transposed tile: Cs[row = tile col c][col = s]
#pragma unroll
    for (int j = 0; j < 4; j++) {
      const int c = wn + j * 16 + fr;
      const float bb = SM ? 0.f : bias[((wn >> 4) + j) * 512 + bx * 16 + fr];
#pragma unroll
      for (int i = 0; i < 4; i++) {
        us4 w;
#pragma unroll
        for (int r = 0; r < 4; r++) w.v[r] = f2bf(acc[i][j][r] + bb);
        *(us4*)&Cs[c * CW + wm + i * 16 + ((lane >> 4) << 2)] = w;
      }
    }
  } else {
#pragma unroll
    for (int j = 0; j < NJ; j++) {
      const int c = wn + j * 16 + fr;
#pragma unroll
      for (int i = 0; i < 4; i++) {
        const int rbase = wm + i * 16 + ((lane >> 4) << 2);
#pragma unroll
        for (int r = 0; r < 4; r++)
          Cs[(rbase + r) * CW + c] = f2bf(acc[i][j][r]);
      }
    }
  }
  __syncthreads();

  // ---- coalesced copy-out ----
  u16* dst = (u16*)Cv;
  if constexpr (MODE == M_PROJQ) {
    // qsP[b][s][bx*128 + c], rows 4096 wide
    const int b = m0 >> 11, s0 = m0 & 2047;
    const long base = (long)b * 8388608 + (long)s0 * 4096 + bx * 128;
#pragma unroll
    for (int it = 0; it < 8; it++) {
      const int idx = it * 256 + tid;
      const int row = idx >> 4, ch = idx & 15;
      *(uint4*)&dst[base + (long)row * 4096 + ch * 8] = *(const uint4*)&Cs[row * CW + ch * 8];
    }
  } else if constexpr (MODE == M_PROJT) {
    // [b,h,e,s]: row c -> h=c>>4, e=bx*16+(c&15)
    const int b = m0 >> 11, s0 = m0 & 2047;
#pragma unroll
    for (int it = 0; it < 8; it++) {
      const int idx = it * 256 + tid;
      const int row = idx >> 4, ch = idx & 15;
      const long base = (long)(b * 8 + (row >> 4)) * 1048576 +
                        (long)(bx * 16 + (row & 15)) * 2048 + s0;
      *(uint4*)&dst[base + ch * 8] = *(const uint4*)&Cs[row * CW + ch * 8];
    }
  } else if constexpr (MODE == M_PLAIN) {
    const long base = (long)z * sCz + (long)m0 * ldc + n0;
    constexpr int CH = BN / 8;  // 16B chunks per row
#pragma unroll
    for (int it = 0; it < 128 * CH / 256; it++) {
      const int idx = it * 256 + tid;
      const int row = idx / CH, ch = idx % CH;
      *(uint4*)&dst[base + (long)row * ldc + ch * 8] = *(const uint4*)&Cs[row * CW + ch * 8];
    }
  } else {  // M_OUT: out2[b][s][h*512 + n0 + c]
    const long base = (long)(z >> 3) * 8388608 + (long)m0 * 4096 + (z & 7) * 512 + n0;
#pragma unroll
    for (int it = 0; it < 8; it++) {
      const int idx = it * 256 + tid;
      const int row = idx >> 4, ch = idx & 15;
      *(uint4*)&dst[base + (long)row * 4096 + ch * 8] = *(const uint4*)&Cs[row * CW + ch * 8];
    }
  }
}

// merged fp32 -> bf16 convert of q,k,v (2048 blocks each)
__global__ void cvt3_kernel(const float* __restrict__ q, const float* __restrict__ k,
                            const float* __restrict__ v, u16* __restrict__ qb,
                            u16* __restrict__ kb, u16* __restrict__ vb) {
  const int arr = blockIdx.x >> 11;
  const int lb = blockIdx.x & 2047;
  const float* in = arr == 0 ? q : (arr == 1 ? k : v);
  u16* out = arr == 0 ? qb : (arr == 1 ? kb : vb);
  const long i = ((long)lb * 256 + threadIdx.x) * 8;
  float4 a = *(const float4*)(in + i);
  float4 b = *(const float4*)(in + i + 4);
  u16 t[8] = {f2bf(a.x), f2bf(a.y), f2bf(a.z), f2bf(a.w),
              f2bf(b.x), f2bf(b.y), f2bf(b.z), f2bf(b.w)};
  uint4 w; __builtin_memcpy(&w, t, 16);
  *(uint4*)(out + i) = w;
}

// merged Wq/Wk/Wv transpose+convert with h-interleave:
// WT[(e>>4)*128 + h*16 + (e&15)][d] = bf16(W[h][d][e])
__global__ void tcvt3_kernel(const float* __restrict__ Wq, const float* __restrict__ Wk,
                             const float* __restrict__ Wv, u16* __restrict__ WqT,
                             u16* __restrict__ WkT, u16* __restrict__ WvT)
{
  __shared__ float tile[32][33];
  const int arr = blockIdx.z >> 3;
  const int h = blockIdx.z & 7;
  const float* in = (arr == 0 ? Wq : (arr == 1 ? Wk : Wv)) + (long)h * 262144;
  u16* out = arr == 0 ? WqT : (arr == 1 ? WkT : WvT);
  const int c0 = blockIdx.x * 32, r0 = blockIdx.y * 32;  // c=e cols, r=d rows of in
#pragma unroll
  for (int yy = threadIdx.y; yy < 32; yy += 8)
    tile[yy][threadIdx.x] = in[(long)(r0 + yy) * 512 + c0 + threadIdx.x];
  __syncthreads();
#pragma unroll
  for (int yy = threadIdx.y; yy < 32; yy += 8) {
    const int e = c0 + yy;
    const int rowp = ((e >> 4) << 7) + h * 16 + (e & 15);
    out[(long)rowp * 512 + r0 + threadIdx.x] = f2bf(tile[threadIdx.x][yy]);
  }
}

// WoT[f][c] = bf16(Wo[(c&511)*8 + (c>>9)][f]); Wo [4096][512] fp32, WoT [512][4096]
__global__ void tcvt_wo(const float* __restrict__ in, u16* __restrict__ out) {
  __shared__ float tile[32][33];
  const int c0 = blockIdx.x * 32, f0 = blockIdx.y * 32;
  const int h = c0 >> 9, j0 = c0 & 511;
#pragma unroll
  for (int yy = threadIdx.y; yy < 32; yy += 8)
    tile[yy][threadIdx.x] = in[(long)((j0 + yy) * 8 + h) * 512 + f0 + threadIdx.x];
  __syncthreads();
#pragma unroll
  for (int yy = threadIdx.y; yy < 32; yy += 8)
    out[(long)(f0 + yy) * 4096 + c0 + threadIdx.x] = f2bf(tile[threadIdx.x][yy]);
}

// sum 4 fp32 K-split partials + bias -> fp32 out; 8192x512 elems, float4
__global__ void reduce4_kernel(const float* __restrict__ p, const float* __restrict__ bo,
                               float* __restrict__ out)
{
  const long S = 8192L * 512;
  const long i4 = ((long)blockIdx.x * 256 + threadIdx.x) * 4;
  float4 a = *(const float4*)(p + i4);
  float4 b = *(const float4*)(p + S + i4);
  float4 c = *(const float4*)(p + 2 * S + i4);
  float4 d = *(const float4*)(p + 3 * S + i4);
  float4 bb = *(const float4*)(bo + (i4 & 511));
  float4 r;
  r.x = a.x + b.x + c.x + d.x + bb.x;
  r.y = a.y + b.y + c.y + d.y + bb.y;
  r.z = a.z + b.z + c.z + d.z + bb.z;
  r.w = a.w + b.w + c.w + d.w + bb.w;
  *(float4*)(out + i4) = r;
}

extern "C" void kernel_launch(void* const* d_in, const int* in_sizes, int n_in,
                              void* d_out, int out_size, void* d_ws, size_t ws_size,
                              hipStream_t stream) {
  const float* q  = (const float*)d_in[0];
  const float* k  = (const float*)d_in[1];
  const float* v  = (const float*)d_in[2];
  const float* Wq = (const float*)d_in[3];
  const float* bq = (const float*)d_in[4];
  const float* Wk = (const float*)d_in[5];
  const float* bk = (const float*)d_in[6];
  const float* Wv = (const float*)d_in[7];
  const float* bv = (const float*)d_in[8];
  const float* Wo = (const float*)d_in[9];
  const float* bo = (const float*)d_in[10];
  float* outp = (float*)d_out;

  char* ws = (char*)d_ws;
  // time-aliased layout (peak 212 MiB):
  u16* qs   = (u16*)(ws);                  //   0- 64 MiB qsP [b][s][perm(h,d)]
  float* Pf = (float*)(ws);                //   0- 64 MiB fp32 K-split partials (qs dead)
  u16* WqT  = (u16*)(ws + (64L  << 20));   //  64- 68     dead before ksT written
  u16* qb   = (u16*)(ws + (72L  << 20));   //  72- 80     dead before ksT written
  u16* ksT  = (u16*)(ws + (64L  << 20));   //  64-128 [b,h,e,s]; later out2
  u16* out2 = ksT;                         //  64-128 [b,s,(h*512+j)]
  u16* kb   = (u16*)(ws + (128L << 20));   // 128-136     dead before vsT written
  u16* vsT  = (u16*)(ws + (128L << 20));   // 128-192 [b,h,e,s]
  u16* vb   = (u16*)(ws + (192L << 20));   // 192-200     dead before ctxT written
  u16* WkT  = (u16*)(ws + (200L << 20));   // 200-204     dead before ctxT written
  u16* WvT  = (u16*)(ws + (204L << 20));   // 204-208     dead before ctxT written
  u16* ctxT = (u16*)(ws + (192L << 20));   // 192-208 [b,h][j][d]
  u16* WoT  = (u16*)(ws + (208L << 20));   // 208-212 [f][h*512+j]

  // 1. fp32 -> bf16 inputs
  cvt3_kernel<<<6144, 256, 0, stream>>>(q, k, v, qb, kb, vb);

  // 2. weight transposes (h-interleaved rows for Wq/Wk/Wv)
  dim3 tb(32, 8, 1);
  tcvt3_kernel<<<dim3(16, 16, 24), tb, 0, stream>>>(Wq, Wk, Wv, WqT, WkT, WvT);
  tcvt_wo<<<dim3(128, 16, 1), tb, 0, stream>>>(Wo, WoT);

  // 3-5. projections (softmax fused for q,k): M=8192, N=4096(h-interleaved), K=512
  gemm_kernel<M_PROJQ, 128, true><<<2048, 256, 0, stream>>>(
      qb, 0, 512, WqT, 0, 512, bq, qs, 0, 0, 32, 512);
  gemm_kernel<M_PROJT, 128, true><<<2048, 256, 0, stream>>>(
      kb, 0, 512, WkT, 0, 512, bk, ksT, 0, 0, 32, 512);
  gemm_kernel<M_PROJT, 128, false><<<2048, 256, 0, stream>>>(
      vb, 0, 512, WvT, 0, 512, bv, vsT, 0, 0, 32, 512);

  // 6. ctxT[b,h][j][d] = sum_s vsT[j][s]*ksT[d][s]; BN=128: nx=4, ny=4, nz=32 -> 512
  gemm_kernel<M_PLAIN, 128, false><<<512, 256, 0, stream>>>(
      vsT, 1048576, 2048, ksT, 1048576, 2048, nullptr, ctxT, 262144, 512, 4, 2048);

  // 7. out2[b][s][h*512+j] = sum_d qsP[s][perm(h,d)]*ctxT[j][d]; nx=4, ny=16, nz=32
  gemm_kernel<M_OUT, 128, false><<<2048, 256, 0, stream>>>(
      qs, 0, 4096, ctxT, 262144, 512, nullptr, out2, 0, 0, 4, 512);

  // 8. final partials: K=4096 split 4x1024; nx=4, ny=64, nz=4 -> 1024 blocks
  gemm_kernel<M_FINAL, 128, false><<<1024, 256, 0, stream>>>(
      out2, 1024, 4096, WoT, 1024, 4096, nullptr, Pf, 8192L * 512, 512, 4, 1024);

  // 9. reduce partials + bias -> fp32 out
  reduce4_kernel<<<4096, 256, 0, stream>>>(Pf, bo, outp);
}

// Round 7
// 302.540 us; speedup vs baseline: 1.1846x; 1.1787x over previous
//
#include <hip/hip_runtime.h>
#include <hip/hip_bf16.h>

typedef unsigned short u16;
typedef __bf16 bf16x8_t __attribute__((ext_vector_type(8)));
typedef float f32x4_t __attribute__((ext_vector_type(4)));

struct alignas(8) us4 { u16 v[4]; };

__device__ __forceinline__ u16 f2bf(float f) {
  __hip_bfloat16 h = __float2bfloat16(f);
  u16 u; __builtin_memcpy(&u, &h, 2); return u;
}

__device__ __forceinline__ void gload16(const u16* g, u16* l) {
  __builtin_amdgcn_global_load_lds(
      (const __attribute__((address_space(1))) void*)g,
      (__attribute__((address_space(3))) void*)l, 16, 0, 0);
}

#define M_PROJQ 0
#define M_PROJT 1
#define M_PLAIN 2
#define M_W2    3
#define M_FINAL 4
#define M_CTXS  5

// C[m][n] = sum_k A[m][k] * Bt[n][k], bf16, 128x128 tile, BK=32.
// 2-buf depth-1 prefetch (r4-proven): ds_read cur -> stage next -> MFMA -> sync.
// PROJ modes: weights pre-interleaved (row' = (e>>4)*128 + h*16 + (e&15));
//   SM=true fuses softmax-over-heads in the epilogue (cross-wave LDS exchange).
//   M_PROJQ -> qsP[b][s][(d>>4)*128+h*16+(d&15)]; M_PROJT -> [b,h,e,s].
// M_PLAIN: batched z, bf16 C. M_W2: z=(b,h), writes W2Pt[b][f][perm(h,d)].
// M_CTXS: z=(kc,bh) K-split ctx, fp32 partials. M_FINAL: z=(b,kc), fp32 partials.
template<int MODE, bool SM>
__global__ __launch_bounds__(256, 2)
void gemm_kernel(const u16* __restrict__ A, long sAz, int lda,
                 const u16* __restrict__ B, long sBz, int ldb,
                 const float* __restrict__ bias,
                 void* __restrict__ Cv, long sCz, int ldc,
                 int nx, int ny, int K)
{
  __shared__ __align__(16) u16 smem[17408];  // 2 x 8192 staging bufs; reused as Cs

  // XCD-bijective swizzle (gridDim.x % 8 == 0 for all launches here)
  const int nwg = gridDim.x;
  const int chunk = nwg >> 3;
  const int bid = blockIdx.x;
  const int wg = (bid & 7) * chunk + (bid >> 3);
  const int nxy = nx * ny;
  const int z = wg / nxy;
  const int rem = wg - z * nxy;
  const int by = rem / nx;
  const int bx = rem - by * nx;

  const int tid = threadIdx.x;
  const int lane = tid & 63;
  const int wave = tid >> 6;
  const int wm = (wave >> 1) * 64;
  const int wn = (wave & 1) * 64;
  const int m0 = by * 128;
  const int n0 = bx * 128;

  // per-mode batch/base offsets
  const u16* Az; const u16* Bz;
  if constexpr (MODE == M_CTXS) {
    const int bh = z & 31, kc = z >> 5;
    Az = A + (long)bh * 1048576 + kc * 1024;
    Bz = B + (long)bh * 1048576 + kc * 1024;
  } else if constexpr (MODE == M_W2) {
    Az = A + (long)z * 262144;
    Bz = B + (long)(z & 7) * 262144;
  } else if constexpr (MODE == M_FINAL) {
    Az = A + (long)(z >> 2) * 8388608 + (z & 3) * 1024;
    Bz = B + (long)(z >> 2) * 2097152 + (z & 3) * 1024;
  } else {
    Az = A + (long)z * sAz;
    Bz = B + (long)z * sBz;
  }

  const int srow = tid >> 2;            // 0..63
  const int scol = (tid & 3) * 8;       // 0,8,16,24
  const u16* aptr0 = Az + (long)(m0 + srow) * lda + scol;
  const u16* aptr1 = aptr0 + (long)64 * lda;
  const u16* bptr0 = Bz + (long)(n0 + srow) * ldb + scol;
  const u16* bptr1 = bptr0 + (long)64 * ldb;

  f32x4_t acc[4][4];
#pragma unroll
  for (int i = 0; i < 4; i++)
#pragma unroll
    for (int j = 0; j < 4; j++) acc[i][j] = (f32x4_t){0.f, 0.f, 0.f, 0.f};

  const int kk = (lane >> 4) * 8;
  const int fr = lane & 15;
  const int nt = K >> 5;

  int aoffL[4], boffL[4];
#pragma unroll
  for (int i = 0; i < 4; i++) aoffL[i] = (wm + i * 16 + fr) * 32 + kk;
#pragma unroll
  for (int j = 0; j < 4; j++) boffL[j] = 4096 + (wn + j * 16 + fr) * 32 + kk;

  // prologue: stage tile 0 into buf 0
  gload16(aptr0, smem + tid * 8);
  gload16(aptr1, smem + 2048 + tid * 8);
  gload16(bptr0, smem + 4096 + tid * 8);
  gload16(bptr1, smem + 6144 + tid * 8);
  __syncthreads();

  int cur = 0;
  for (int t = 0; t < nt - 1; t++) {
    const u16* cb = smem + cur * 8192;
    bf16x8_t afr[4], bfr[4];
#pragma unroll
    for (int i = 0; i < 4; i++) afr[i] = *(const bf16x8_t*)&cb[aoffL[i]];
#pragma unroll
    for (int j = 0; j < 4; j++) bfr[j] = *(const bf16x8_t*)&cb[boffL[j]];
    u16* nb = smem + (cur ^ 1) * 8192;
    const int ko = (t + 1) * 32;
    gload16(aptr0 + ko, nb + tid * 8);
    gload16(aptr1 + ko, nb + 2048 + tid * 8);
    gload16(bptr0 + ko, nb + 4096 + tid * 8);
    gload16(bptr1 + ko, nb + 6144 + tid * 8);
#pragma unroll
    for (int i = 0; i < 4; i++)
#pragma unroll
      for (int j = 0; j < 4; j++)
        acc[i][j] = __builtin_amdgcn_mfma_f32_16x16x32_bf16(afr[i], bfr[j], acc[i][j], 0, 0, 0);
    __syncthreads();
    cur ^= 1;
  }
  {  // last tile: compute only
    const u16* cb = smem + cur * 8192;
    bf16x8_t afr[4], bfr[4];
#pragma unroll
    for (int i = 0; i < 4; i++) afr[i] = *(const bf16x8_t*)&cb[aoffL[i]];
#pragma unroll
    for (int j = 0; j < 4; j++) bfr[j] = *(const bf16x8_t*)&cb[boffL[j]];
#pragma unroll
    for (int i = 0; i < 4; i++)
#pragma unroll
      for (int j = 0; j < 4; j++)
        acc[i][j] = __builtin_amdgcn_mfma_f32_16x16x32_bf16(afr[i], bfr[j], acc[i][j], 0, 0, 0);
  }
  __syncthreads();  // all LDS reads done before smem reuse

  // ---- fused softmax over heads (PROJ modes, SM=true) ----
  if constexpr (SM) {
    // lane holds rows wm+i*16+(lane>>4)*4+r, cols h=(wn>>4)+j (j=0..3), e=bx*16+fr.
    // Partner wave (wave^1) holds the other 4 heads for identical rows/e.
    float* ex = (float*)smem;          // stride 17 -> conflict-free
    float* ex2 = ex + 4352;
    const int wmg = wave >> 1, wng = wave & 1;
    const int self = ((wmg * 2 + wng) * 64 + lane) * 17;
    const int part = ((wmg * 2 + (wng ^ 1)) * 64 + lane) * 17;
    float bj[4];
#pragma unroll
    for (int j = 0; j < 4; j++) bj[j] = bias[((wn >> 4) + j) * 512 + bx * 16 + fr];
#pragma unroll
    for (int i = 0; i < 4; i++)
#pragma unroll
      for (int j = 0; j < 4; j++)
#pragma unroll
        for (int r = 0; r < 4; r++) acc[i][j][r] += bj[j];
    float mx[16];
#pragma unroll
    for (int i = 0; i < 4; i++)
#pragma unroll
      for (int r = 0; r < 4; r++) {
        float m = acc[i][0][r];
#pragma unroll
        for (int j = 1; j < 4; j++) m = fmaxf(m, acc[i][j][r]);
        mx[i * 4 + r] = m;
      }
#pragma unroll
    for (int t = 0; t < 16; t++) ex[self + t] = mx[t];
    __syncthreads();
#pragma unroll
    for (int t = 0; t < 16; t++) mx[t] = fmaxf(mx[t], ex[part + t]);
    float sm[16];
#pragma unroll
    for (int t = 0; t < 16; t++) sm[t] = 0.f;
#pragma unroll
    for (int i = 0; i < 4; i++)
#pragma unroll
      for (int j = 0; j < 4; j++)
#pragma unroll
        for (int r = 0; r < 4; r++) {
          float p = __expf(acc[i][j][r] - mx[i * 4 + r]);
          acc[i][j][r] = p;
          sm[i * 4 + r] += p;
        }
#pragma unroll
    for (int t = 0; t < 16; t++) ex2[self + t] = sm[t];
    __syncthreads();
#pragma unroll
    for (int t = 0; t < 16; t++) sm[t] = 1.f / (sm[t] + ex2[part + t]);
#pragma unroll
    for (int i = 0; i < 4; i++)
#pragma unroll
      for (int j = 0; j < 4; j++)
#pragma unroll
        for (int r = 0; r < 4; r++) acc[i][j][r] *= sm[i * 4 + r];
    __syncthreads();  // exchange reads done before Cs reuse
  }

  // C/D frag layout: col = lane&15 (+wn+j*16), row = (lane>>4)*4 + reg (+wm+i*16)
  if constexpr (MODE == M_FINAL || MODE == M_CTXS) {
    // direct fp32 partial writes
    float* o;
    if constexpr (MODE == M_FINAL)
      o = (float*)Cv + (long)(z & 3) * 4194304 + (long)(z >> 2) * 1048576;
    else
      o = (float*)Cv + (long)z * 262144;
#pragma unroll
    for (int i = 0; i < 4; i++) {
      const int rbase = m0 + wm + i * 16 + ((lane >> 4) << 2);
#pragma unroll
      for (int j = 0; j < 4; j++) {
        const int gc = n0 + wn + j * 16 + fr;
#pragma unroll
        for (int r = 0; r < 4; r++)
          o[(long)(rbase + r) * ldc + gc] = acc[i][j][r];
      }
    }
    return;
  }

  // ---- LDS-staged epilogue: Cs[128][136] ----
  constexpr int CW = 136;
  u16* Cs = smem;
  if constexpr (MODE == M_PROJT || MODE == M_W2) {
    // transposed tile: Cs[row = tile col c][col = m]
#pragma unroll
    for (int j = 0; j < 4; j++) {
      const int c = wn + j * 16 + fr;
      float bb = 0.f;
      if constexpr (MODE == M_PROJT) bb = SM ? 0.f : bias[((wn >> 4) + j) * 512 + bx * 16 + fr];
#pragma unroll
      for (int i = 0; i < 4; i++) {
        us4 w;
#pragma unroll
        for (int r = 0; r < 4; r++) w.v[r] = f2bf(acc[i][j][r] + bb);
        *(us4*)&Cs[c * CW + wm + i * 16 + ((lane >> 4) << 2)] = w;
      }
    }
  } else {
#pragma unroll
    for (int j = 0; j < 4; j++) {
      const int c = wn + j * 16 + fr;
#pragma unroll
      for (int i = 0; i < 4; i++) {
        const int rbase = wm + i * 16 + ((lane >> 4) << 2);
#pragma unroll
        for (int r = 0; r < 4; r++)
          Cs[(rbase + r) * CW + c] = f2bf(acc[i][j][r]);
      }
    }
  }
  __syncthreads();

  // ---- coalesced copy-out ----
  u16* dst = (u16*)Cv;
  if constexpr (MODE == M_PROJQ) {
    // qsP[b][s][bx*128 + c], rows 4096 wide
    const int b = m0 >> 11, s0 = m0 & 2047;
    const long base = (long)b * 8388608 + (long)s0 * 4096 + bx * 128;
#pragma unroll
    for (int it = 0; it < 8; it++) {
      const int idx = it * 256 + tid;
      const int row = idx >> 4, ch = idx & 15;
      *(uint4*)&dst[base + (long)row * 4096 + ch * 8] = *(const uint4*)&Cs[row * CW + ch * 8];
    }
  } else if constexpr (MODE == M_PROJT) {
    // [b,h,e,s]: Cs row c -> h=c>>4, e=bx*16+(c&15)
    const int b = m0 >> 11, s0 = m0 & 2047;
#pragma unroll
    for (int it = 0; it < 8; it++) {
      const int idx = it * 256 + tid;
      const int row = idx >> 4, ch = idx & 15;
      const long base = (long)(b * 8 + (row >> 4)) * 1048576 +
                        (long)(bx * 16 + (row & 15)) * 2048 + s0;
      *(uint4*)&dst[base + ch * 8] = *(const uint4*)&Cs[row * CW + ch * 8];
    }
  } else if constexpr (MODE == M_W2) {
    // W2Pt[b][f][(m0+dd)>>4 *128 + h*16 + (dd&15)], Cs row = f-col, col = dd
    const int b = z >> 3, h = z & 7;
    const long base0 = (long)b * 2097152 + (long)n0 * 4096 + ((m0 >> 4) << 7) + h * 16;
#pragma unroll
    for (int it = 0; it < 4; it++) {
      const int idx = it * 256 + tid;
      const int row = idx >> 3, ch = idx & 7;   // row: f 0..127, ch: dd-block 0..7
      const long base = base0 + (long)row * 4096 + ch * 128;
      *(uint4*)&dst[base] = *(const uint4*)&Cs[row * CW + ch * 16];
      *(uint4*)&dst[base + 8] = *(const uint4*)&Cs[row * CW + ch * 16 + 8];
    }
  } else {  // M_PLAIN
    const long base = (long)z * sCz + (long)m0 * ldc + n0;
#pragma unroll
    for (int it = 0; it < 8; it++) {
      const int idx = it * 256 + tid;
      const int row = idx >> 4, ch = idx & 15;
      *(uint4*)&dst[base + (long)row * ldc + ch * 8] = *(const uint4*)&Cs[row * CW + ch * 8];
    }
  }
}

// merged fp32 -> bf16 convert of q,k,v
__global__ void cvt3_kernel(const float* __restrict__ q, const float* __restrict__ k,
                            const float* __restrict__ v, u16* __restrict__ qb,
                            u16* __restrict__ kb, u16* __restrict__ vb) {
  const int arr = blockIdx.x >> 11;
  const int lb = blockIdx.x & 2047;
  const float* in = arr == 0 ? q : (arr == 1 ? k : v);
  u16* out = arr == 0 ? qb : (arr == 1 ? kb : vb);
  const long i = ((long)lb * 256 + threadIdx.x) * 8;
  float4 a = *(const float4*)(in + i);
  float4 b = *(const float4*)(in + i + 4);
  u16 t[8] = {f2bf(a.x), f2bf(a.y), f2bf(a.z), f2bf(a.w),
              f2bf(b.x), f2bf(b.y), f2bf(b.z), f2bf(b.w)};
  uint4 w; __builtin_memcpy(&w, t, 16);
  *(uint4*)(out + i) = w;
}

// merged Wq/Wk/Wv transpose+convert with h-interleave:
// WT[(e>>4)*128 + h*16 + (e&15)][d] = bf16(W[h][d][e])
__global__ void tcvt3_kernel(const float* __restrict__ Wq, const float* __restrict__ Wk,
                             const float* __restrict__ Wv, u16* __restrict__ WqT,
                             u16* __restrict__ WkT, u16* __restrict__ WvT)
{
  __shared__ float tile[32][33];
  const int arr = blockIdx.z >> 3;
  const int h = blockIdx.z & 7;
  const float* in = (arr == 0 ? Wq : (arr == 1 ? Wk : Wv)) + (long)h * 262144;
  u16* out = arr == 0 ? WqT : (arr == 1 ? WkT : WvT);
  const int c0 = blockIdx.x * 32, r0 = blockIdx.y * 32;  // c=e cols, r=d rows of in
#pragma unroll
  for (int yy = threadIdx.y; yy < 32; yy += 8)
    tile[yy][threadIdx.x] = in[(long)(r0 + yy) * 512 + c0 + threadIdx.x];
  __syncthreads();
#pragma unroll
  for (int yy = threadIdx.y; yy < 32; yy += 8) {
    const int e = c0 + yy;
    const int rowp = ((e >> 4) << 7) + h * 16 + (e & 15);
    out[(long)rowp * 512 + r0 + threadIdx.x] = f2bf(tile[threadIdx.x][yy]);
  }
}

// WoT2[h][f][e] = bf16(Wo[e*8+h][f]); Wo [4096][512] fp32
__global__ void tcvt_wo2(const float* __restrict__ in, u16* __restrict__ out) {
  __shared__ float tile[32][33];
  const int h = blockIdx.z;
  const int e0 = blockIdx.x * 32, f0 = blockIdx.y * 32;
#pragma unroll
  for (int yy = threadIdx.y; yy < 32; yy += 8)
    tile[yy][threadIdx.x] = in[(long)((e0 + yy) * 8 + h) * 512 + f0 + threadIdx.x];
  __syncthreads();
#pragma unroll
  for (int yy = threadIdx.y; yy < 32; yy += 8)
    out[(long)h * 262144 + (long)(f0 + yy) * 512 + e0 + threadIdx.x] =
        f2bf(tile[threadIdx.x][yy]);
}

// sum 4 fp32 K-split partials + bias -> fp32 out; 8192x512 elems
__global__ void reduce4_kernel(const float* __restrict__ p, const float* __restrict__ bo,
                               float* __restrict__ out)
{
  const long S = 8192L * 512;
  const long i4 = ((long)blockIdx.x * 256 + threadIdx.x) * 4;
  float4 a = *(const float4*)(p + i4);
  float4 b = *(const float4*)(p + S + i4);
  float4 c = *(const float4*)(p + 2 * S + i4);
  float4 d = *(const float4*)(p + 3 * S + i4);
  float4 bb = *(const float4*)(bo + (i4 & 511));
  float4 r;
  r.x = a.x + b.x + c.x + d.x + bb.x;
  r.y = a.y + b.y + c.y + d.y + bb.y;
  r.z = a.z + b.z + c.z + d.z + bb.z;
  r.w = a.w + b.w + c.w + d.w + bb.w;
  *(float4*)(out + i4) = r;
}

// sum 2 fp32 ctx partials -> bf16 ctx; 32*512*512 elems, 8/thread
__global__ void reduce2c_kernel(const float* __restrict__ p, u16* __restrict__ out)
{
  const long S = 32L * 262144;
  const long i = ((long)blockIdx.x * 256 + threadIdx.x) * 8;
  float4 a0 = *(const float4*)(p + i);
  float4 a1 = *(const float4*)(p + i + 4);
  float4 b0 = *(const float4*)(p + S + i);
  float4 b1 = *(const float4*)(p + S + i + 4);
  u16 t[8] = {f2bf(a0.x + b0.x), f2bf(a0.y + b0.y), f2bf(a0.z + b0.z), f2bf(a0.w + b0.w),
              f2bf(a1.x + b1.x), f2bf(a1.y + b1.y), f2bf(a1.z + b1.z), f2bf(a1.w + b1.w)};
  uint4 w; __builtin_memcpy(&w, t, 16);
  *(uint4*)(out + i) = w;
}

extern "C" void kernel_launch(void* const* d_in, const int* in_sizes, int n_in,
                              void* d_out, int out_size, void* d_ws, size_t ws_size,
                              hipStream_t stream) {
  const float* q  = (const float*)d_in[0];
  const float* k  = (const float*)d_in[1];
  const float* v  = (const float*)d_in[2];
  const float* Wq = (const float*)d_in[3];
  const float* bq = (const float*)d_in[4];
  const float* Wk = (const float*)d_in[5];
  const float* bk = (const float*)d_in[6];
  const float* Wv = (const float*)d_in[7];
  const float* bv = (const float*)d_in[8];
  const float* Wo = (const float*)d_in[9];
  const float* bo = (const float*)d_in[10];
  float* outp = (float*)d_out;

  char* ws = (char*)d_ws;
  // time-aliased layout (peak 212 MiB base; ctx-split partials optional at 212+):
  u16* qs    = (u16*)(ws);                  //   0- 64 qsP [b][s][perm(h,d)]; live to final
  u16* WqT   = (u16*)(ws + (64L  << 20));   //  64- 68  dead before ksT written
  u16* qb    = (u16*)(ws + (72L  << 20));   //  72- 80  dead before ksT written
  u16* ksT   = (u16*)(ws + (64L  << 20));   //  64-128 [b,h,e,s]; dead after ctx
  u16* W2Pt  = (u16*)(ws + (64L  << 20));   //  64- 80 [b][f][perm(h,d)] after ctx
  u16* kb    = (u16*)(ws + (128L << 20));   // 128-136  dead before vsT written
  u16* vsT   = (u16*)(ws + (128L << 20));   // 128-192 [b,h,e,s]; dead after ctx
  float* Pf  = (float*)(ws + (128L << 20)); // 128-192 final K-split partials
  u16* vb    = (u16*)(ws + (192L << 20));   // 192-200  dead before ctx written
  u16* WkT   = (u16*)(ws + (200L << 20));   // 200-204  dead before ctx written
  u16* WvT   = (u16*)(ws + (204L << 20));   // 204-208  dead before ctx written
  u16* ctxT  = (u16*)(ws + (192L << 20));   // 192-208 ctx [b,h][d][e]
  u16* WoT2  = (u16*)(ws + (208L << 20));   // 208-212 [h][f][e]
  float* Pfc = (float*)(ws + (212L << 20)); // 212-276 ctx K-split partials (guarded)
  const bool ctx_split = ws_size >= (286L << 20);

  // 1. fp32 -> bf16 inputs
  cvt3_kernel<<<6144, 256, 0, stream>>>(q, k, v, qb, kb, vb);

  // 2. weight transposes (h-interleaved rows for Wq/Wk/Wv; per-head Wo)
  dim3 tb(32, 8, 1);
  tcvt3_kernel<<<dim3(16, 16, 24), tb, 0, stream>>>(Wq, Wk, Wv, WqT, WkT, WvT);
  tcvt_wo2<<<dim3(16, 16, 8), tb, 0, stream>>>(Wo, WoT2);

  // 3-5. projections (softmax fused for q,k): M=8192, N=4096, K=512
  gemm_kernel<M_PROJQ, true><<<2048, 256, 0, stream>>>(
      qb, 0, 512, WqT, 0, 512, bq, qs, 0, 0, 32, 64, 512);
  gemm_kernel<M_PROJT, true><<<2048, 256, 0, stream>>>(
      kb, 0, 512, WkT, 0, 512, bk, ksT, 0, 0, 32, 64, 512);
  gemm_kernel<M_PROJT, false><<<2048, 256, 0, stream>>>(
      vb, 0, 512, WvT, 0, 512, bv, vsT, 0, 0, 32, 64, 512);

  // 6. ctx[b,h][d][e] = sum_s ksT[d][s]*vsT[e][s]; M=N=512, K=2048, 32 batches
  if (ctx_split) {
    gemm_kernel<M_CTXS, false><<<1024, 256, 0, stream>>>(
        ksT, 0, 2048, vsT, 0, 2048, nullptr, Pfc, 0, 512, 4, 4, 1024);
    reduce2c_kernel<<<4096, 256, 0, stream>>>(Pfc, ctxT);
  } else {
    gemm_kernel<M_PLAIN, false><<<512, 256, 0, stream>>>(
        ksT, 1048576, 2048, vsT, 1048576, 2048, nullptr, ctxT, 262144, 512, 4, 4, 2048);
  }

  // 7. W2Pt[b][f][perm(h,d)] = sum_e ctx[b,h][d][e]*WoT2[h][f][e]; 32 batches 512^3
  gemm_kernel<M_W2, false><<<512, 256, 0, stream>>>(
      ctxT, 262144, 512, WoT2, 0, 512, nullptr, W2Pt, 0, 0, 4, 4, 512);

  // 8. final partials: Pf[kc][b*2048+s][f] = sum_c qsP[b][s][c]*W2Pt[b][f][c],
  //    K=4096 split 4x1024; z=(b,kc), grid 4*16*4*4 = 1024
  gemm_kernel<M_FINAL, false><<<1024, 256, 0, stream>>>(
      qs, 0, 4096, W2Pt, 0, 4096, nullptr, Pf, 0, 512, 4, 16, 1024);

  // 9. reduce partials + bias -> fp32 out
  reduce4_kernel<<<4096, 256, 0, stream>>>(Pf, bo, outp);
}